// Round 2
// baseline (177.127 us; speedup 1.0000x reference)
//
#include <hip/hip_runtime.h>

// VQ-VAE quantizer: h (256,512,32) fp32, embeddings (1024,32) fp32.
// d_out (fp32): quantized_st [4194304] | indices [131072] | loss [131072]
//
// R14: SINGLE-sweep certified filter with register bitmask candidate
// collection. Diagnosis from R13: removing VALU ops (48->40% busy) did NOT
// reduce duration -> kernel is latency/issue-bound at 4 waves/SIMD (LDS cap),
// so the lever is fewer iterations/memory events, not fewer VALU ops.
// The 2-sweep structure existed only because the threshold isn't known until
// sweep 1 ends. Replacement:
//   - per (lane,slot): u64 tile bitmask (2x u32) + lane-local max bsloc.
//   - candidate test dv >= thr_s, thr_s = stale cross-lane groupmax - margin,
//     refreshed every 16 tiles (4-shuffle reduce). thr_s <= M - margin always
//     -> true argmin's bit ALWAYS set (superset). Mask covers all 64 tiles ->
//     no overflow possible at collection.
//   - at each refresh, lanes with bsloc < thr_s clear masks (provable junk:
//     all their values < M_running - margin <= M - margin).
//   - publish to LDS lists ONCE post-sweep (atomics out of hot loop);
//     exact tails unchanged (bit-exact numpy recheck -> final argmin exact).
//   - margin on dot scale: fmaf(sar, 1.5*2^-17, 4e-5); proven bound is
//     2*delta + E2MAX/2 <= sar*2^-17 + 1.53e-5 (bf16 product err sar*2^-18
//     per value, e uniform +-2^-10 -> e2 <= 3.05e-5). >=50% headroom/term.
//   - depth-2 register prefetch on the 28-tile global segment.
// Hot loop: 64 iters, 64 tile loads, 128 MFMAs/wave (was 128/128/256).
// History: R3 270 -> R5 193 -> R8 141 -> R9 131 -> R12 126 (scan 64.5) ->
//          R13 126 (scan 66.2, VALU 40%, Mfma 10%, latency-bound).

#define EMB_N 1024
#define DIM 32
#define NVEC (256 * 512)
#define NTILES (EMB_N / 16)
#define NT_LDS 36
#define MAXC 8

typedef unsigned long long u64;
typedef unsigned int u32;
typedef unsigned short ushortT;
typedef __attribute__((ext_vector_type(8))) short bf16x8;
typedef __attribute__((ext_vector_type(4))) float f32x4;

__device__ __forceinline__ u32 enc_f32(float x) {
    u32 u = __float_as_uint(x);
    return (u & 0x80000000u) ? ~u : (u | 0x80000000u);  // monotone order-preserving
}
__device__ __forceinline__ ushortT f2bf(float f) {  // RNE fp32->bf16
    u32 u = __float_as_uint(f);
    return (ushortT)((u + 0x7FFFu + ((u >> 16) & 1u)) >> 16);
}
__device__ __forceinline__ u64 shflx_u64(u64 x, int m) {
    int lo = __shfl_xor((int)(u32)x, m);
    int hi = __shfl_xor((int)(x >> 32), m);
    return ((u64)(u32)hi << 32) | (u32)lo;
}

// numpy pairwise ||x||^2, n=32: 8 accumulators stride 8, fixed combine tree
__device__ __forceinline__ float norm2_np(const float* fr) {
    float sq[DIM];
#pragma unroll
    for (int i = 0; i < DIM; ++i) sq[i] = fr[i] * fr[i];
    float r[8];
#pragma unroll
    for (int j = 0; j < 8; ++j)
        r[j] = ((sq[j] + sq[j + 8]) + sq[j + 16]) + sq[j + 24];
    return ((r[0] + r[1]) + (r[2] + r[3])) + ((r[4] + r[5]) + (r[6] + r[7]));
}

// ---- prep: e2 + bf16 B-frag table. frag(nt,lane,j) = bf16(emb[nt*16+(lane&15)][(lane>>4)*8+j])
__global__ __launch_bounds__(256) void prep_kernel(
    const float* __restrict__ emb, float* __restrict__ e2,
    ushortT* __restrict__ bfrag)
{
#pragma clang fp contract(off)
    const int t = blockIdx.x * 256 + threadIdx.x;    // 0..4095
    const int l = t & 63;
    const int row = ((t >> 6) << 4) + (l & 15);
    const int k0 = (l >> 4) * 8;
    const float* ep = emb + (size_t)row * DIM + k0;
    ushortT* dst = bfrag + (size_t)t * 8;
#pragma unroll
    for (int j = 0; j < 8; ++j) dst[j] = f2bf(ep[j]);
    if (t < EMB_N) {
        const float* e = emb + (size_t)t * DIM;
        float tmp[DIM];
#pragma unroll
        for (int i = 0; i < DIM; ++i) tmp[i] = e[i];
        e2[t] = norm2_np(tmp);
    }
}

// single-sweep body: 2 MFMA -> per-slot {cand-bit vs stale thr, lane max}
#define SBODY(BVAL, MASK, BIT) do {                                                 \
    f32x4 d0 = __builtin_amdgcn_mfma_f32_16x16x32_bf16(afr0, (BVAL), zacc, 0, 0, 0);\
    f32x4 d1 = __builtin_amdgcn_mfma_f32_16x16x32_bf16(afr1, (BVAL), zacc, 0, 0, 0);\
    _Pragma("unroll")                                                               \
    for (int i = 0; i < 8; ++i) {                                                   \
        float dv = (i >> 2) ? d1[i & 3] : d0[i & 3];                                \
        MASK[i] |= (dv >= thr_s[i]) ? (BIT) : 0u;                                   \
        bsloc[i] = fmaxf(bsloc[i], dv);                                             \
    }                                                                               \
} while (0)

#define SLDS(NT, MASK, BIT) do {                                                    \
    bf16x8 bql = *(const bf16x8*)(s_b + (NT) * 512 + lane * 8);                     \
    SBODY(bql, MASK, BIT);                                                          \
} while (0)

// cross-lane refresh: thr_s = groupmax(bsloc) - mg; clear provably-junk masks
#define SHARE() do {                                                                \
    _Pragma("unroll")                                                               \
    for (int i = 0; i < 8; ++i) {                                                   \
        float t_ = bsloc[i];                                                        \
        t_ = fmaxf(t_, __shfl_xor(t_, 1));                                          \
        t_ = fmaxf(t_, __shfl_xor(t_, 2));                                          \
        t_ = fmaxf(t_, __shfl_xor(t_, 4));                                          \
        t_ = fmaxf(t_, __shfl_xor(t_, 8));                                          \
        thr_s[i] = t_ - mg[i];                                                      \
        bool keep_ = (bsloc[i] >= thr_s[i]);                                        \
        ml[i] = keep_ ? ml[i] : 0u;                                                 \
        mh[i] = keep_ ? mh[i] : 0u;                                                 \
    }                                                                               \
} while (0)

// ---- fused scan: split-table, 1 wave = 32 rows, bitmask collect, fused tail ----
__global__ __launch_bounds__(256) void vq_scan(
    const float* __restrict__ h,
    const float* __restrict__ emb,
    const float* __restrict__ e2,
    const ushortT* __restrict__ bfrag,
    float* __restrict__ out_q, float* __restrict__ out_idx,
    float* __restrict__ out_loss)
{
#pragma clang fp contract(off)
    __shared__ __align__(16) ushortT s_b[NT_LDS * 512];   // 36 KB
    __shared__ u32     lds_cnt[4][32];                    // 512 B
    __shared__ ushortT lds_cand[4][32 * MAXC];            // 2 KB

    // cooperative stage of the LDS half: 36 KB = 2304 uint4
    {
        const uint4* src = (const uint4*)bfrag;
        uint4* dst = (uint4*)s_b;
        for (int o = threadIdx.x; o < NT_LDS * 64; o += 256) dst[o] = src[o];
    }

    const int wslot = threadIdx.x >> 6;
    const int wid   = (blockIdx.x * 256 + threadIdx.x) >> 6;  // 0..4095
    const int lane  = threadIdx.x & 63;
    const int col16 = lane & 15;
    const int quad  = lane >> 4;
    const size_t row0 = (size_t)wid * 32;

    u32*     cnt  = lds_cnt[wslot];    // wave-private
    ushortT* cand = lds_cand[wslot];
    if (lane < 32) cnt[lane] = 0;

    // A-frags for rows row0+col16 (tile0), row0+16+col16 (tile1); fp32 abs-sums
    bf16x8 afr0, afr1;
    float sa0, sa1;
    {
        const float* ap = h + (row0 + col16) * DIM + quad * 8;
        float4 x = *(const float4*)ap, y = *(const float4*)(ap + 4);
        afr0[0]=(short)f2bf(x.x); afr0[1]=(short)f2bf(x.y); afr0[2]=(short)f2bf(x.z); afr0[3]=(short)f2bf(x.w);
        afr0[4]=(short)f2bf(y.x); afr0[5]=(short)f2bf(y.y); afr0[6]=(short)f2bf(y.z); afr0[7]=(short)f2bf(y.w);
        sa0 = fabsf(x.x)+fabsf(x.y)+fabsf(x.z)+fabsf(x.w)+fabsf(y.x)+fabsf(y.y)+fabsf(y.z)+fabsf(y.w);
        const float* bp = ap + 16 * DIM;
        float4 u = *(const float4*)bp, v = *(const float4*)(bp + 4);
        afr1[0]=(short)f2bf(u.x); afr1[1]=(short)f2bf(u.y); afr1[2]=(short)f2bf(u.z); afr1[3]=(short)f2bf(u.w);
        afr1[4]=(short)f2bf(v.x); afr1[5]=(short)f2bf(v.y); afr1[6]=(short)f2bf(v.z); afr1[7]=(short)f2bf(v.w);
        sa1 = fabsf(u.x)+fabsf(u.y)+fabsf(u.z)+fabsf(u.w)+fabsf(v.x)+fabsf(v.y)+fabsf(v.z)+fabsf(v.w);
    }
    sa0 += __shfl_xor(sa0, 16); sa0 += __shfl_xor(sa0, 32);
    sa1 += __shfl_xor(sa1, 16); sa1 += __shfl_xor(sa1, 32);

    __syncthreads();   // LDS half staged (lists are wave-private; no hazard)

    const f32x4 zacc = {0.f, 0.f, 0.f, 0.f};

    // per-slot state: lane max, stale group threshold, margin, 64-bit tile mask
    float bsloc[8], thr_s[8], mg[8];
    u32 ml[8], mh[8];
#pragma unroll
    for (int i = 0; i < 8; ++i) {
        bsloc[i] = -3.4e38f; thr_s[i] = -3.4e38f; ml[i] = 0u; mh[i] = 0u;
        float sar = __shfl((i >> 2) ? sa1 : sa0, quad * 4 + (i & 3));
        mg[i] = __builtin_fmaf(sar, 0x1.8p-17f, 4.0e-5f);
    }

    // ---- single sweep over 64 tiles ----
    SLDS(0, ml, 1u);
    SHARE();                       // establish a real threshold; prune tile-0 junk
#pragma unroll
    for (int nt = 1; nt < 16; ++nt) SLDS(nt, ml, 1u << nt);
    SHARE();
#pragma unroll
    for (int nt = 16; nt < 32; ++nt) SLDS(nt, ml, 1u << nt);
    SHARE();
#pragma unroll
    for (int nt = 32; nt < NT_LDS; ++nt) SLDS(nt, mh, 1u << (nt - 32));

    // global segment (tiles 36..63) with depth-2 register prefetch
    bf16x8 p0 = *(const bf16x8*)(bfrag + 36 * 512 + lane * 8);
    bf16x8 p1 = *(const bf16x8*)(bfrag + 37 * 512 + lane * 8);
#pragma unroll
    for (int nt = 36; nt < 48; ++nt) {
        bf16x8 nx = *(const bf16x8*)(bfrag + (nt + 2) * 512 + lane * 8);
        SBODY(p0, mh, 1u << (nt - 32));
        p0 = p1; p1 = nx;
    }
    SHARE();
#pragma unroll
    for (int nt = 48; nt < 62; ++nt) {
        bf16x8 nx = *(const bf16x8*)(bfrag + (nt + 2) * 512 + lane * 8);
        SBODY(p0, mh, 1u << (nt - 32));
        p0 = p1; p1 = nx;
    }
    SBODY(p0, mh, 1u << 30);
    SBODY(p1, mh, 1u << 31);
    SHARE();   // final: thr_s = M - mg; masks now hold only certified-window bits

    // ---- publish candidates to wave-private LDS lists (once, post-sweep) ----
#pragma unroll
    for (int i = 0; i < 8; ++i) {
        if (bsloc[i] >= thr_s[i]) {          // kept lane(s) for this row
            const int rloc = ((i >> 2) << 4) + quad * 4 + (i & 3);
            u32 m0 = ml[i];
            while (m0) {
                int b = __ffs(m0) - 1; m0 &= m0 - 1;
                u32 slot = atomicAdd(&cnt[rloc], 1u);
                if (slot < MAXC) cand[rloc * MAXC + slot] = (ushortT)((b << 4) + col16);
            }
            u32 m1 = mh[i];
            while (m1) {
                int b = __ffs(m1) - 1; m1 &= m1 - 1;
                u32 slot = atomicAdd(&cnt[rloc], 1u);
                if (slot < MAXC) cand[rloc * MAXC + slot] = (ushortT)(((b + 32) << 4) + col16);
            }
        }
    }

    // ---- tail A: overflowed rows (rare) -> wave-cooperative exact scan ----
    u64 ovf = __ballot((lane < 32) && (cnt[lane & 31] > MAXC));
    while (ovf) {
        const int r = (int)(__ffsll((unsigned long long)ovf) - 1);
        ovf &= ovf - 1;
        const float* fp = h + (row0 + r) * DIM;   // wave-uniform row
        float fu[DIM];
#pragma unroll
        for (int i = 0; i < DIM; i += 4) {
            float4 x = *(const float4*)(fp + i);
            fu[i] = x.x; fu[i + 1] = x.y; fu[i + 2] = x.z; fu[i + 3] = x.w;
        }
        const float f2 = norm2_np(fu);
        u64 bk = ~0ull;
        for (int c = lane; c < EMB_N; c += 64) {
            const float* ep = emb + (size_t)c * DIM;
            float a = 0.f;
#pragma unroll
            for (int k = 0; k < DIM; ++k) a = __builtin_fmaf(fu[k], ep[k], a);
            float dd = (f2 + e2[c]) - (2.0f * a);
            u64 key = ((u64)enc_f32(dd) << 32) | (u32)c;
            if (key < bk) bk = key;
        }
#pragma unroll
        for (int m = 1; m < 64; m <<= 1) {
            u64 o = shflx_u64(bk, m);
            if (o < bk) bk = o;
        }
        if (lane == 0) { cand[r * MAXC] = (ushortT)(bk & 1023u); cnt[r] = 1; }
    }

    // ---- tail B: owner lane per row -> recheck + epilogue ----
    if (lane < 32) {
        const int row = (int)row0 + lane;
        const u32 n = cnt[lane];
        const float* f = h + (size_t)row * DIM;
        float fr[DIM];
#pragma unroll
        for (int i = 0; i < DIM; i += 4) {
            float4 x = *(const float4*)(f + i);
            fr[i] = x.x; fr[i + 1] = x.y; fr[i + 2] = x.z; fr[i + 3] = x.w;
        }
        int bidx;
        if (n == 1) {
            bidx = (int)cand[lane * MAXC];       // sole certified qualifier
        } else {
            const float f2 = norm2_np(fr);
            u64 best = ~0ull;
            for (u32 j = 0; j < n; ++j) {
                const u32 c = (u32)cand[lane * MAXC + j];
                const float* ep = emb + (size_t)c * DIM;
                float a = 0.f;
#pragma unroll
                for (int k = 0; k < DIM; ++k) a = __builtin_fmaf(fr[k], ep[k], a);  // BLAS chain
                float dd = (f2 + e2[c]) - (2.0f * a);     // exact numpy formula
                u64 key = ((u64)enc_f32(dd) << 32) | c;
                if (key < best) best = key;
            }
            bidx = (int)(best & 0xFFFFFFFFu);
        }

        const float* qv = emb + (size_t)bidx * DIM;
        float ps = 0.f;
#pragma unroll
        for (int i = 0; i < DIM; i += 4) {
            float4 qx; qx.x = qv[i]; qx.y = qv[i+1]; qx.z = qv[i+2]; qx.w = qv[i+3];
            float dx = qx.x - fr[i], dy = qx.y - fr[i+1], dz = qx.z - fr[i+2], dw = qx.w - fr[i+3];
            ps += dx * dx; ps += dy * dy; ps += dz * dz; ps += dw * dw;
            float4 o;
            o.x = fr[i]     + (qx.x - fr[i]);
            o.y = fr[i + 1] + (qx.y - fr[i + 1]);
            o.z = fr[i + 2] + (qx.z - fr[i + 2]);
            o.w = fr[i + 3] + (qx.w - fr[i + 3]);
            *(float4*)(out_q + (size_t)row * DIM + i) = o;
        }
        float m = ps * (1.0f / DIM);
        out_idx[row]  = (float)bidx;
        out_loss[row] = m * 0.1f + m * 0.1f;
    }
}

// ---------- fallback (R3-style) if workspace too small ----------
__global__ void e2_kernel(const float* __restrict__ emb, float* __restrict__ e2) {
#pragma clang fp contract(off)
    int c = blockIdx.x * blockDim.x + threadIdx.x;
    if (c >= EMB_N) return;
    const float* e = emb + (size_t)c * DIM;
    float tmp[DIM];
#pragma unroll
    for (int i = 0; i < DIM; ++i) tmp[i] = e[i];
    e2[c] = norm2_np(tmp);
}

__global__ __launch_bounds__(256) void vq_kernel(
    const float* __restrict__ h, const float* __restrict__ emb,
    const float* __restrict__ e2, float* __restrict__ out_q,
    float* __restrict__ out_idx, float* __restrict__ out_loss)
{
#pragma clang fp contract(off)
    const int v = blockIdx.x * blockDim.x + threadIdx.x;
    const float* f = h + (size_t)v * DIM;
    float fr[DIM];
#pragma unroll
    for (int i = 0; i < DIM; i += 4) {
        float4 x = *(const float4*)(f + i);
        fr[i] = x.x; fr[i + 1] = x.y; fr[i + 2] = x.z; fr[i + 3] = x.w;
    }
    const float f2 = norm2_np(fr);
    float best = 3.4e38f; int bidx = 0;
#pragma unroll 1
    for (int c = 0; c < EMB_N; ++c) {
        const float* e = emb + (size_t)c * DIM;
        float a0 = 0.f;
#pragma unroll
        for (int k = 0; k < DIM; ++k) a0 = __builtin_fmaf(fr[k], e[k], a0);
        float d0 = (f2 + e2[c]) - (2.0f * a0);
        if (d0 < best) { best = d0; bidx = c; }
    }
    const float* q = emb + (size_t)bidx * DIM;
    float ps = 0.f;
#pragma unroll
    for (int i = 0; i < DIM; i += 4) {
        float4 qx; qx.x = q[i]; qx.y = q[i+1]; qx.z = q[i+2]; qx.w = q[i+3];
        float dx = qx.x - fr[i], dy = qx.y - fr[i+1], dz = qx.z - fr[i+2], dw = qx.w - fr[i+3];
        ps += dx * dx; ps += dy * dy; ps += dz * dz; ps += dw * dw;
        float4 o;
        o.x = fr[i] + (qx.x - fr[i]); o.y = fr[i+1] + (qx.y - fr[i+1]);
        o.z = fr[i+2] + (qx.z - fr[i+2]); o.w = fr[i+3] + (qx.w - fr[i+3]);
        *(float4*)(out_q + (size_t)v * DIM + i) = o;
    }
    float m = ps * (1.0f / DIM);
    out_idx[v]  = (float)bidx;
    out_loss[v] = m * 0.1f + m * 0.1f;
}

extern "C" void kernel_launch(void* const* d_in, const int* in_sizes, int n_in,
                              void* d_out, int out_size, void* d_ws, size_t ws_size,
                              hipStream_t stream) {
    const float* h   = (const float*)d_in[0];
    const float* emb = (const float*)d_in[1];
    float* out = (float*)d_out;
    float* out_q    = out;                               // 4194304
    float* out_idx  = out + (size_t)NVEC * DIM;          // 131072
    float* out_loss = out + (size_t)NVEC * DIM + NVEC;   // 131072

    // ws layout: e2 4KB | bfrag 64KB
    float*   e2    = (float*)d_ws;
    ushortT* bfrag = (ushortT*)((char*)d_ws + 4096);
    const size_t need = 4096 + (size_t)EMB_N * DIM * sizeof(ushortT);

    if (ws_size >= need) {
        prep_kernel<<<16, 256, 0, stream>>>(emb, e2, bfrag);
        vq_scan<<<1024, 256, 0, stream>>>(h, emb, e2, bfrag,
                                          out_q, out_idx, out_loss);
    } else {
        e2_kernel<<<EMB_N / 256, 256, 0, stream>>>(emb, e2);
        vq_kernel<<<NVEC / 256, 256, 0, stream>>>(h, emb, e2, out_q, out_idx, out_loss);
    }
}

// Round 3
// 111.483 us; speedup vs baseline: 1.5888x; 1.5888x over previous
//
#include <hip/hip_runtime.h>

// VQ-VAE quantizer: h (256,512,32) fp32, embeddings (1024,32) fp32.
// d_out (fp32): quantized_st [4194304] | indices [131072] | loss [131072]
//
// R15: codebook-split wave pairs for 2x occupancy at R12's register cost.
// Post-mortems: R13 (fewer VALU ops, same time) -> latency-bound, not
// VALU-throughput-bound. R14 (single sweep, bitmask state) -> VGPR 56->224,
// occupancy 9%, 157us: wave-state registers are the scarcest resource.
// R15 keeps the lean 2-sweep body (56 VGPR class) and doubles WAVES instead:
//   - wave pair shares 32 rows; wave h scans tiles nt = 2k+h (k=0..31):
//     18 LDS + 14 global tiles each (balanced halves of the 36/28 split).
//   - sweep1: per-wave group max; pairs exchange 32 per-row maxes via 1KB
//     LDS (sm), one barrier -> combined full-codebook max -> threshold.
//   - sweep2: bit-identical recompute, append qualifiers to PAIR-shared LDS
//     list (atomic; order-independent u64-key recheck in tail).
//   - tails (A: overflow exact scan, B: exact numpy recheck + epilogue) run
//     on the h==0 wave of each pair; bit-exact argmin unchanged.
//   - raw-dot ranking (no e2 in hot loop) with PROVEN margin:
//     2*delta + E2MAX/2 <= sar*2^-17 + 1.53e-5  (delta <= sar*2^-18,
//     e2 <= 32/1024^2);  mg = fmaf(sar, 1.5*2^-17, 4e-5) -> >=50% headroom.
//   - block 512 thr = 4 pairs; grid 1024; LDS 36864+1024+512+2048 = 40448B
//     -> 4 blocks/CU -> 32 waves/CU (grid-matched: 8192 waves total).
// Totals unchanged vs R12: 1M MFMAs, 524K tile-loads; waves 4096 -> 8192.
// History: R3 270 -> R5 193 -> R8 141 -> R9 131 -> R12 126 (scan 64.5,
//          occ 34%) -> R13 126 (VALU 40%, latency-bound) -> R14 177 (VGPR
//          224, occ 9% -- reverted).

#define EMB_N 1024
#define DIM 32
#define NVEC (256 * 512)
#define NTILES (EMB_N / 16)
#define NT_LDS 36
#define MAXC 8

typedef unsigned long long u64;
typedef unsigned int u32;
typedef unsigned short ushortT;
typedef __attribute__((ext_vector_type(8))) short bf16x8;
typedef __attribute__((ext_vector_type(4))) float f32x4;

__device__ __forceinline__ u32 enc_f32(float x) {
    u32 u = __float_as_uint(x);
    return (u & 0x80000000u) ? ~u : (u | 0x80000000u);  // monotone order-preserving
}
__device__ __forceinline__ ushortT f2bf(float f) {  // RNE fp32->bf16
    u32 u = __float_as_uint(f);
    return (ushortT)((u + 0x7FFFu + ((u >> 16) & 1u)) >> 16);
}
__device__ __forceinline__ u64 shflx_u64(u64 x, int m) {
    int lo = __shfl_xor((int)(u32)x, m);
    int hi = __shfl_xor((int)(x >> 32), m);
    return ((u64)(u32)hi << 32) | (u32)lo;
}

// numpy pairwise ||x||^2, n=32: 8 accumulators stride 8, fixed combine tree
__device__ __forceinline__ float norm2_np(const float* fr) {
    float sq[DIM];
#pragma unroll
    for (int i = 0; i < DIM; ++i) sq[i] = fr[i] * fr[i];
    float r[8];
#pragma unroll
    for (int j = 0; j < 8; ++j)
        r[j] = ((sq[j] + sq[j + 8]) + sq[j + 16]) + sq[j + 24];
    return ((r[0] + r[1]) + (r[2] + r[3])) + ((r[4] + r[5]) + (r[6] + r[7]));
}

// ---- prep: e2 + bf16 B-frag table. frag(nt,lane,j) = bf16(emb[nt*16+(lane&15)][(lane>>4)*8+j])
__global__ __launch_bounds__(256) void prep_kernel(
    const float* __restrict__ emb, float* __restrict__ e2,
    ushortT* __restrict__ bfrag)
{
#pragma clang fp contract(off)
    const int t = blockIdx.x * 256 + threadIdx.x;    // 0..4095
    const int l = t & 63;
    const int row = ((t >> 6) << 4) + (l & 15);
    const int k0 = (l >> 4) * 8;
    const float* ep = emb + (size_t)row * DIM + k0;
    ushortT* dst = bfrag + (size_t)t * 8;
#pragma unroll
    for (int j = 0; j < 8; ++j) dst[j] = f2bf(ep[j]);
    if (t < EMB_N) {
        const float* e = emb + (size_t)t * DIM;
        float tmp[DIM];
#pragma unroll
        for (int i = 0; i < DIM; ++i) tmp[i] = e[i];
        e2[t] = norm2_np(tmp);
    }
}

// sweep bodies (raw-dot ranking: no e2, no fmaf in hot loop)
#define S1BODY(BEXPR) do {                                                      \
    bf16x8 b = *(const bf16x8*)(BEXPR);                                         \
    f32x4 d0 = __builtin_amdgcn_mfma_f32_16x16x32_bf16(afr0, b, zacc, 0, 0, 0); \
    f32x4 d1 = __builtin_amdgcn_mfma_f32_16x16x32_bf16(afr1, b, zacc, 0, 0, 0); \
    _Pragma("unroll")                                                           \
    for (int r = 0; r < 4; ++r) {                                               \
        bs[r]     = fmaxf(bs[r],     d0[r]);                                    \
        bs[4 + r] = fmaxf(bs[4 + r], d1[r]);                                    \
    }                                                                           \
} while (0)

#define S2BODY(BEXPR, NT) do {                                                  \
    bf16x8 b = *(const bf16x8*)(BEXPR);                                         \
    f32x4 d0 = __builtin_amdgcn_mfma_f32_16x16x32_bf16(afr0, b, zacc, 0, 0, 0); \
    f32x4 d1 = __builtin_amdgcn_mfma_f32_16x16x32_bf16(afr1, b, zacc, 0, 0, 0); \
    const u32 cc = (u32)(NT) * 16 + col16;                                      \
    bool q[8];                                                                  \
    bool any = false;                                                           \
    _Pragma("unroll")                                                           \
    for (int i = 0; i < 8; ++i) {                                               \
        float dv = ((i >> 2) ? d1[i & 3] : d0[i & 3]);                          \
        q[i] = (dv >= thr[i]);                                                  \
        any |= q[i];                                                            \
    }                                                                           \
    if (__ballot(any)) {                                                        \
        _Pragma("unroll")                                                       \
        for (int i = 0; i < 8; ++i) {                                           \
            if (__ballot(q[i])) {                                               \
                if (q[i]) {                                                     \
                    const int rloc = ((i >> 2) << 4) + quad * 4 + (i & 3);      \
                    u32 slot = atomicAdd(&cnt[rloc], 1u);                       \
                    if (slot < MAXC) cand[rloc * MAXC + slot] = (ushortT)cc;    \
                }                                                               \
            }                                                                   \
        }                                                                       \
    }                                                                           \
} while (0)

// ---- fused scan: codebook-split wave pairs, split-table, fused tails ----
__global__ __launch_bounds__(512, 8) void vq_scan(
    const float* __restrict__ h,
    const float* __restrict__ emb,
    const float* __restrict__ e2,
    const ushortT* __restrict__ bfrag,
    float* __restrict__ out_q, float* __restrict__ out_idx,
    float* __restrict__ out_loss)
{
#pragma clang fp contract(off)
    __shared__ __align__(16) ushortT s_b[NT_LDS * 512];   // 36 KB
    __shared__ float   sm[8][32];                         // 1 KB  pair max exchange
    __shared__ u32     lds_cnt[4][32];                    // 512 B per-PAIR lists
    __shared__ ushortT lds_cand[4][32 * MAXC];            // 2 KB

    // cooperative stage of the LDS half: 36 KB = 2304 uint4
    {
        const uint4* src = (const uint4*)bfrag;
        uint4* dst = (uint4*)s_b;
        for (int o = threadIdx.x; o < NT_LDS * 64; o += 512) dst[o] = src[o];
    }

    const int wslot = threadIdx.x >> 6;        // 0..7
    const int pair  = wslot >> 1;              // 0..3
    const int hh    = wslot & 1;               // codebook half
    const int lane  = threadIdx.x & 63;
    const int col16 = lane & 15;
    const int quad  = lane >> 4;
    const size_t row0 = ((size_t)blockIdx.x * 4 + pair) * 32;

    u32*     cnt  = lds_cnt[pair];     // pair-shared
    ushortT* cand = lds_cand[pair];
    if (hh == 0 && lane < 32) cnt[lane] = 0;

    // A-frags for rows row0+col16 (tile0), row0+16+col16 (tile1); fp32 abs-sums
    bf16x8 afr0, afr1;
    float sa0, sa1;
    {
        const float* ap = h + (row0 + col16) * DIM + quad * 8;
        float4 x = *(const float4*)ap, y = *(const float4*)(ap + 4);
        afr0[0]=(short)f2bf(x.x); afr0[1]=(short)f2bf(x.y); afr0[2]=(short)f2bf(x.z); afr0[3]=(short)f2bf(x.w);
        afr0[4]=(short)f2bf(y.x); afr0[5]=(short)f2bf(y.y); afr0[6]=(short)f2bf(y.z); afr0[7]=(short)f2bf(y.w);
        sa0 = fabsf(x.x)+fabsf(x.y)+fabsf(x.z)+fabsf(x.w)+fabsf(y.x)+fabsf(y.y)+fabsf(y.z)+fabsf(y.w);
        const float* bp = ap + 16 * DIM;
        float4 u = *(const float4*)bp, v = *(const float4*)(bp + 4);
        afr1[0]=(short)f2bf(u.x); afr1[1]=(short)f2bf(u.y); afr1[2]=(short)f2bf(u.z); afr1[3]=(short)f2bf(u.w);
        afr1[4]=(short)f2bf(v.x); afr1[5]=(short)f2bf(v.y); afr1[6]=(short)f2bf(v.z); afr1[7]=(short)f2bf(v.w);
        sa1 = fabsf(u.x)+fabsf(u.y)+fabsf(u.z)+fabsf(u.w)+fabsf(v.x)+fabsf(v.y)+fabsf(v.z)+fabsf(v.w);
    }
    sa0 += __shfl_xor(sa0, 16); sa0 += __shfl_xor(sa0, 32);
    sa1 += __shfl_xor(sa1, 16); sa1 += __shfl_xor(sa1, 32);

    __syncthreads();   // LDS table staged + cnt zeroed

    const f32x4 zacc = {0.f, 0.f, 0.f, 0.f};

    // ---- sweep 1 over this wave's half: nt = 2k+hh, k=0..31 ----
    float bs[8];
#pragma unroll
    for (int i = 0; i < 8; ++i) bs[i] = -3.4e38f;
#pragma unroll 2
    for (int k = 0; k < 18; ++k) {             // LDS tiles (nt <= 35)
        const int nt = 2 * k + hh;
        S1BODY(s_b + nt * 512 + lane * 8);
    }
#pragma unroll 2
    for (int k = 18; k < 32; ++k) {            // global tiles (nt >= 36)
        const int nt = 2 * k + hh;
        S1BODY(bfrag + (size_t)nt * 512 + lane * 8);
    }
#pragma unroll
    for (int m = 1; m < 16; m <<= 1)
#pragma unroll
        for (int i = 0; i < 8; ++i) bs[i] = fmaxf(bs[i], __shfl_xor(bs[i], m));

    // ---- pair exchange: combined full-codebook max -> per-row threshold ----
    if (col16 == 0) {
#pragma unroll
        for (int i = 0; i < 8; ++i)
            sm[wslot][((i >> 2) << 4) + quad * 4 + (i & 3)] = bs[i];
    }
    __syncthreads();

    float thr[8];
#pragma unroll
    for (int i = 0; i < 8; ++i) {
        const int rloc = ((i >> 2) << 4) + quad * 4 + (i & 3);
        float m = fmaxf(bs[i], sm[wslot ^ 1][rloc]);
        float sar = __shfl((i >> 2) ? sa1 : sa0, quad * 4 + (i & 3));
        // proven bound: 2*delta + E2MAX/2 <= sar*2^-17 + 1.53e-5; 50% headroom
        thr[i] = m - __builtin_fmaf(sar, 0x1.8p-17f, 4.0e-5f);
    }

    // ---- sweep 2: bit-identical recompute, append to pair-shared lists ----
#pragma unroll 2
    for (int k = 0; k < 18; ++k) {
        const int nt = 2 * k + hh;
        S2BODY(s_b + nt * 512 + lane * 8, nt);
    }
#pragma unroll 2
    for (int k = 18; k < 32; ++k) {
        const int nt = 2 * k + hh;
        S2BODY(bfrag + (size_t)nt * 512 + lane * 8, nt);
    }

    __syncthreads();   // pair lists complete

    if (hh != 0) return;   // tails on one wave per pair

    // ---- tail A: overflowed rows (rare) -> wave-cooperative exact scan ----
    u64 ovf = __ballot((lane < 32) && (cnt[lane & 31] > MAXC));
    while (ovf) {
        const int r = (int)(__ffsll((unsigned long long)ovf) - 1);
        ovf &= ovf - 1;
        const float* fp = h + (row0 + r) * DIM;   // wave-uniform row
        float fu[DIM];
#pragma unroll
        for (int i = 0; i < DIM; i += 4) {
            float4 x = *(const float4*)(fp + i);
            fu[i] = x.x; fu[i + 1] = x.y; fu[i + 2] = x.z; fu[i + 3] = x.w;
        }
        const float f2 = norm2_np(fu);
        u64 bk = ~0ull;
        for (int c = lane; c < EMB_N; c += 64) {
            const float* ep = emb + (size_t)c * DIM;
            float a = 0.f;
#pragma unroll
            for (int k = 0; k < DIM; ++k) a = __builtin_fmaf(fu[k], ep[k], a);
            float dd = (f2 + e2[c]) - (2.0f * a);
            u64 key = ((u64)enc_f32(dd) << 32) | (u32)c;
            if (key < bk) bk = key;
        }
#pragma unroll
        for (int m = 1; m < 64; m <<= 1) {
            u64 o = shflx_u64(bk, m);
            if (o < bk) bk = o;
        }
        if (lane == 0) { cand[r * MAXC] = (ushortT)(bk & 1023u); cnt[r] = 1; }
    }

    // ---- tail B: owner lane per row -> recheck + epilogue ----
    if (lane < 32) {
        const int row = (int)row0 + lane;
        const u32 n = cnt[lane];
        const float* f = h + (size_t)row * DIM;
        float fr[DIM];
#pragma unroll
        for (int i = 0; i < DIM; i += 4) {
            float4 x = *(const float4*)(f + i);
            fr[i] = x.x; fr[i + 1] = x.y; fr[i + 2] = x.z; fr[i + 3] = x.w;
        }
        int bidx;
        if (n == 1) {
            bidx = (int)cand[lane * MAXC];       // sole certified qualifier
        } else {
            const float f2 = norm2_np(fr);
            u64 best = ~0ull;
            for (u32 j = 0; j < n; ++j) {
                const u32 c = (u32)cand[lane * MAXC + j];
                const float* ep = emb + (size_t)c * DIM;
                float a = 0.f;
#pragma unroll
                for (int k = 0; k < DIM; ++k) a = __builtin_fmaf(fr[k], ep[k], a);  // BLAS chain
                float dd = (f2 + e2[c]) - (2.0f * a);     // exact numpy formula
                u64 key = ((u64)enc_f32(dd) << 32) | c;
                if (key < best) best = key;
            }
            bidx = (int)(best & 0xFFFFFFFFu);
        }

        const float* qv = emb + (size_t)bidx * DIM;
        float ps = 0.f;
#pragma unroll
        for (int i = 0; i < DIM; i += 4) {
            float4 qx; qx.x = qv[i]; qx.y = qv[i+1]; qx.z = qv[i+2]; qx.w = qv[i+3];
            float dx = qx.x - fr[i], dy = qx.y - fr[i+1], dz = qx.z - fr[i+2], dw = qx.w - fr[i+3];
            ps += dx * dx; ps += dy * dy; ps += dz * dz; ps += dw * dw;
            float4 o;
            o.x = fr[i]     + (qx.x - fr[i]);
            o.y = fr[i + 1] + (qx.y - fr[i + 1]);
            o.z = fr[i + 2] + (qx.z - fr[i + 2]);
            o.w = fr[i + 3] + (qx.w - fr[i + 3]);
            *(float4*)(out_q + (size_t)row * DIM + i) = o;
        }
        float m = ps * (1.0f / DIM);
        out_idx[row]  = (float)bidx;
        out_loss[row] = m * 0.1f + m * 0.1f;
    }
}

// ---------- fallback (R3-style) if workspace too small ----------
__global__ void e2_kernel(const float* __restrict__ emb, float* __restrict__ e2) {
#pragma clang fp contract(off)
    int c = blockIdx.x * blockDim.x + threadIdx.x;
    if (c >= EMB_N) return;
    const float* e = emb + (size_t)c * DIM;
    float tmp[DIM];
#pragma unroll
    for (int i = 0; i < DIM; ++i) tmp[i] = e[i];
    e2[c] = norm2_np(tmp);
}

__global__ __launch_bounds__(256) void vq_kernel(
    const float* __restrict__ h, const float* __restrict__ emb,
    const float* __restrict__ e2, float* __restrict__ out_q,
    float* __restrict__ out_idx, float* __restrict__ out_loss)
{
#pragma clang fp contract(off)
    const int v = blockIdx.x * blockDim.x + threadIdx.x;
    const float* f = h + (size_t)v * DIM;
    float fr[DIM];
#pragma unroll
    for (int i = 0; i < DIM; i += 4) {
        float4 x = *(const float4*)(f + i);
        fr[i] = x.x; fr[i + 1] = x.y; fr[i + 2] = x.z; fr[i + 3] = x.w;
    }
    const float f2 = norm2_np(fr);
    float best = 3.4e38f; int bidx = 0;
#pragma unroll 1
    for (int c = 0; c < EMB_N; ++c) {
        const float* e = emb + (size_t)c * DIM;
        float a0 = 0.f;
#pragma unroll
        for (int k = 0; k < DIM; ++k) a0 = __builtin_fmaf(fr[k], e[k], a0);
        float d0 = (f2 + e2[c]) - (2.0f * a0);
        if (d0 < best) { best = d0; bidx = c; }
    }
    const float* q = emb + (size_t)bidx * DIM;
    float ps = 0.f;
#pragma unroll
    for (int i = 0; i < DIM; i += 4) {
        float4 qx; qx.x = q[i]; qx.y = q[i+1]; qx.z = q[i+2]; qx.w = q[i+3];
        float dx = qx.x - fr[i], dy = qx.y - fr[i+1], dz = qx.z - fr[i+2], dw = qx.w - fr[i+3];
        ps += dx * dx; ps += dy * dy; ps += dz * dz; ps += dw * dw;
        float4 o;
        o.x = fr[i] + (qx.x - fr[i]); o.y = fr[i+1] + (qx.y - fr[i+1]);
        o.z = fr[i+2] + (qx.z - fr[i+2]); o.w = fr[i+3] + (qx.w - fr[i+3]);
        *(float4*)(out_q + (size_t)v * DIM + i) = o;
    }
    float m = ps * (1.0f / DIM);
    out_idx[v]  = (float)bidx;
    out_loss[v] = m * 0.1f + m * 0.1f;
}

extern "C" void kernel_launch(void* const* d_in, const int* in_sizes, int n_in,
                              void* d_out, int out_size, void* d_ws, size_t ws_size,
                              hipStream_t stream) {
    const float* h   = (const float*)d_in[0];
    const float* emb = (const float*)d_in[1];
    float* out = (float*)d_out;
    float* out_q    = out;                               // 4194304
    float* out_idx  = out + (size_t)NVEC * DIM;          // 131072
    float* out_loss = out + (size_t)NVEC * DIM + NVEC;   // 131072

    // ws layout: e2 4KB | bfrag 64KB
    float*   e2    = (float*)d_ws;
    ushortT* bfrag = (ushortT*)((char*)d_ws + 4096);
    const size_t need = 4096 + (size_t)EMB_N * DIM * sizeof(ushortT);

    if (ws_size >= need) {
        prep_kernel<<<16, 256, 0, stream>>>(emb, e2, bfrag);
        vq_scan<<<1024, 512, 0, stream>>>(h, emb, e2, bfrag,
                                          out_q, out_idx, out_loss);
    } else {
        e2_kernel<<<EMB_N / 256, 256, 0, stream>>>(emb, e2);
        vq_kernel<<<NVEC / 256, 256, 0, stream>>>(h, emb, e2, out_q, out_idx, out_loss);
    }
}

// Round 4
// 107.595 us; speedup vs baseline: 1.6462x; 1.0361x over previous
//
#include <hip/hip_runtime.h>

// VQ-VAE quantizer: h (256,512,32) fp32, embeddings (1024,32) fp32.
// d_out (fp32): quantized_st [4194304] | indices [131072] | loss [131072]
//
// R16: R15 (codebook-split wave pairs, 2-sweep certified filter) with
// sweep 2's append machinery replaced by branch-free register bitmasks.
// Post-mortem R15: occ 34->52%, scan 64.5->54us; VALU 38% + MFMA 12% issue,
// ~50% idle. S2's per-tile cost (8 cmp + 2 SALU ballots + divergent branches
// + LDS atomics ~30 slots/tile, plus the bank-conflict hotspot) is the
// largest remaining per-tile overhead. R14 showed 64-tile-scope mask state
// blows VGPRs; after the codebook split each wave scans only 32 tiles ->
// per-slot mask is ONE u32 (8 VGPRs, inside the 32->64 headroom at
// 8 waves/SIMD). S2 body: cm[i] |= (dv>=thr[i]) ? bit : 0  (~16 VALU, no
// SALU, no atomics, no branches); publish once post-sweep to pair lists.
// Selection set bit-identical to R15 -> exact tails unchanged (bit-exact
// numpy argmin). Everything else identical to R15:
//   - wave pair shares 32 rows; wave h scans tiles nt=2k+h (18 LDS + 14
//     global each); pair max exchange via 1KB LDS -> threshold
//     thr = M - fmaf(sar, 1.5*2^-17, 4e-5) (proven: 2*delta + E2MAX/2 <=
//     sar*2^-17 + 1.53e-5).
//   - tails on h==0 wave: A overflow exact scan, B exact numpy recheck.
//   - block 512 = 4 pairs, grid 1024, LDS 40448B -> 4 blocks/CU -> 32 w/CU.
// History: R3 270 -> R5 193 -> R8 141 -> R9 131 -> R12 126 (occ 34) ->
//          R13 126 (latency-bound) -> R14 177 (VGPR 224 blowup) ->
//          R15 111.5 (scan 54, occ 52%, VGPR 32).

#define EMB_N 1024
#define DIM 32
#define NVEC (256 * 512)
#define NTILES (EMB_N / 16)
#define NT_LDS 36
#define MAXC 8

typedef unsigned long long u64;
typedef unsigned int u32;
typedef unsigned short ushortT;
typedef __attribute__((ext_vector_type(8))) short bf16x8;
typedef __attribute__((ext_vector_type(4))) float f32x4;

__device__ __forceinline__ u32 enc_f32(float x) {
    u32 u = __float_as_uint(x);
    return (u & 0x80000000u) ? ~u : (u | 0x80000000u);  // monotone order-preserving
}
__device__ __forceinline__ ushortT f2bf(float f) {  // RNE fp32->bf16
    u32 u = __float_as_uint(f);
    return (ushortT)((u + 0x7FFFu + ((u >> 16) & 1u)) >> 16);
}
__device__ __forceinline__ u64 shflx_u64(u64 x, int m) {
    int lo = __shfl_xor((int)(u32)x, m);
    int hi = __shfl_xor((int)(x >> 32), m);
    return ((u64)(u32)hi << 32) | (u32)lo;
}

// numpy pairwise ||x||^2, n=32: 8 accumulators stride 8, fixed combine tree
__device__ __forceinline__ float norm2_np(const float* fr) {
    float sq[DIM];
#pragma unroll
    for (int i = 0; i < DIM; ++i) sq[i] = fr[i] * fr[i];
    float r[8];
#pragma unroll
    for (int j = 0; j < 8; ++j)
        r[j] = ((sq[j] + sq[j + 8]) + sq[j + 16]) + sq[j + 24];
    return ((r[0] + r[1]) + (r[2] + r[3])) + ((r[4] + r[5]) + (r[6] + r[7]));
}

// ---- prep: e2 + bf16 B-frag table. frag(nt,lane,j) = bf16(emb[nt*16+(lane&15)][(lane>>4)*8+j])
__global__ __launch_bounds__(256) void prep_kernel(
    const float* __restrict__ emb, float* __restrict__ e2,
    ushortT* __restrict__ bfrag)
{
#pragma clang fp contract(off)
    const int t = blockIdx.x * 256 + threadIdx.x;    // 0..4095
    const int l = t & 63;
    const int row = ((t >> 6) << 4) + (l & 15);
    const int k0 = (l >> 4) * 8;
    const float* ep = emb + (size_t)row * DIM + k0;
    ushortT* dst = bfrag + (size_t)t * 8;
#pragma unroll
    for (int j = 0; j < 8; ++j) dst[j] = f2bf(ep[j]);
    if (t < EMB_N) {
        const float* e = emb + (size_t)t * DIM;
        float tmp[DIM];
#pragma unroll
        for (int i = 0; i < DIM; ++i) tmp[i] = e[i];
        e2[t] = norm2_np(tmp);
    }
}

// sweep 1 body (raw-dot ranking: no e2, no fmaf in hot loop)
#define S1BODY(BEXPR) do {                                                      \
    bf16x8 b = *(const bf16x8*)(BEXPR);                                         \
    f32x4 d0 = __builtin_amdgcn_mfma_f32_16x16x32_bf16(afr0, b, zacc, 0, 0, 0); \
    f32x4 d1 = __builtin_amdgcn_mfma_f32_16x16x32_bf16(afr1, b, zacc, 0, 0, 0); \
    _Pragma("unroll")                                                           \
    for (int r = 0; r < 4; ++r) {                                               \
        bs[r]     = fmaxf(bs[r],     d0[r]);                                    \
        bs[4 + r] = fmaxf(bs[4 + r], d1[r]);                                    \
    }                                                                           \
} while (0)

// sweep 2 body: bit-identical recompute; branch-free mask accumulate.
// K = wave-local tile index 0..31 (nt = 2K+hh); cc decoded at publish.
#define S2BODY(BEXPR, K) do {                                                   \
    bf16x8 b = *(const bf16x8*)(BEXPR);                                         \
    f32x4 d0 = __builtin_amdgcn_mfma_f32_16x16x32_bf16(afr0, b, zacc, 0, 0, 0); \
    f32x4 d1 = __builtin_amdgcn_mfma_f32_16x16x32_bf16(afr1, b, zacc, 0, 0, 0); \
    const u32 bit = 1u << (K);                                                  \
    _Pragma("unroll")                                                           \
    for (int i = 0; i < 8; ++i) {                                               \
        float dv = ((i >> 2) ? d1[i & 3] : d0[i & 3]);                          \
        cm[i] |= (dv >= thr[i]) ? bit : 0u;                                     \
    }                                                                           \
} while (0)

// ---- fused scan: codebook-split wave pairs, mask collect, fused tails ----
__global__ __launch_bounds__(512, 8) void vq_scan(
    const float* __restrict__ h,
    const float* __restrict__ emb,
    const float* __restrict__ e2,
    const ushortT* __restrict__ bfrag,
    float* __restrict__ out_q, float* __restrict__ out_idx,
    float* __restrict__ out_loss)
{
#pragma clang fp contract(off)
    __shared__ __align__(16) ushortT s_b[NT_LDS * 512];   // 36 KB
    __shared__ float   sm[8][32];                         // 1 KB  pair max exchange
    __shared__ u32     lds_cnt[4][32];                    // 512 B per-PAIR lists
    __shared__ ushortT lds_cand[4][32 * MAXC];            // 2 KB

    // cooperative stage of the LDS half: 36 KB = 2304 uint4
    {
        const uint4* src = (const uint4*)bfrag;
        uint4* dst = (uint4*)s_b;
        for (int o = threadIdx.x; o < NT_LDS * 64; o += 512) dst[o] = src[o];
    }

    const int wslot = threadIdx.x >> 6;        // 0..7
    const int pair  = wslot >> 1;              // 0..3
    const int hh    = wslot & 1;               // codebook half
    const int lane  = threadIdx.x & 63;
    const int col16 = lane & 15;
    const int quad  = lane >> 4;
    const size_t row0 = ((size_t)blockIdx.x * 4 + pair) * 32;

    u32*     cnt  = lds_cnt[pair];     // pair-shared
    ushortT* cand = lds_cand[pair];
    if (hh == 0 && lane < 32) cnt[lane] = 0;

    // A-frags for rows row0+col16 (tile0), row0+16+col16 (tile1); fp32 abs-sums
    bf16x8 afr0, afr1;
    float sa0, sa1;
    {
        const float* ap = h + (row0 + col16) * DIM + quad * 8;
        float4 x = *(const float4*)ap, y = *(const float4*)(ap + 4);
        afr0[0]=(short)f2bf(x.x); afr0[1]=(short)f2bf(x.y); afr0[2]=(short)f2bf(x.z); afr0[3]=(short)f2bf(x.w);
        afr0[4]=(short)f2bf(y.x); afr0[5]=(short)f2bf(y.y); afr0[6]=(short)f2bf(y.z); afr0[7]=(short)f2bf(y.w);
        sa0 = fabsf(x.x)+fabsf(x.y)+fabsf(x.z)+fabsf(x.w)+fabsf(y.x)+fabsf(y.y)+fabsf(y.z)+fabsf(y.w);
        const float* bp = ap + 16 * DIM;
        float4 u = *(const float4*)bp, v = *(const float4*)(bp + 4);
        afr1[0]=(short)f2bf(u.x); afr1[1]=(short)f2bf(u.y); afr1[2]=(short)f2bf(u.z); afr1[3]=(short)f2bf(u.w);
        afr1[4]=(short)f2bf(v.x); afr1[5]=(short)f2bf(v.y); afr1[6]=(short)f2bf(v.z); afr1[7]=(short)f2bf(v.w);
        sa1 = fabsf(u.x)+fabsf(u.y)+fabsf(u.z)+fabsf(u.w)+fabsf(v.x)+fabsf(v.y)+fabsf(v.z)+fabsf(v.w);
    }
    sa0 += __shfl_xor(sa0, 16); sa0 += __shfl_xor(sa0, 32);
    sa1 += __shfl_xor(sa1, 16); sa1 += __shfl_xor(sa1, 32);

    __syncthreads();   // LDS table staged + cnt zeroed

    const f32x4 zacc = {0.f, 0.f, 0.f, 0.f};

    // ---- sweep 1 over this wave's half: nt = 2k+hh, k=0..31 ----
    float bs[8];
#pragma unroll
    for (int i = 0; i < 8; ++i) bs[i] = -3.4e38f;
#pragma unroll 2
    for (int k = 0; k < 18; ++k) {             // LDS tiles (nt <= 35)
        const int nt = 2 * k + hh;
        S1BODY(s_b + nt * 512 + lane * 8);
    }
#pragma unroll 2
    for (int k = 18; k < 32; ++k) {            // global tiles (nt >= 36)
        const int nt = 2 * k + hh;
        S1BODY(bfrag + (size_t)nt * 512 + lane * 8);
    }
#pragma unroll
    for (int m = 1; m < 16; m <<= 1)
#pragma unroll
        for (int i = 0; i < 8; ++i) bs[i] = fmaxf(bs[i], __shfl_xor(bs[i], m));

    // ---- pair exchange: combined full-codebook max -> per-row threshold ----
    if (col16 == 0) {
#pragma unroll
        for (int i = 0; i < 8; ++i)
            sm[wslot][((i >> 2) << 4) + quad * 4 + (i & 3)] = bs[i];
    }
    __syncthreads();

    float thr[8];
#pragma unroll
    for (int i = 0; i < 8; ++i) {
        const int rloc = ((i >> 2) << 4) + quad * 4 + (i & 3);
        float m = fmaxf(bs[i], sm[wslot ^ 1][rloc]);
        float sar = __shfl((i >> 2) ? sa1 : sa0, quad * 4 + (i & 3));
        // proven bound: 2*delta + E2MAX/2 <= sar*2^-17 + 1.53e-5; 50% headroom
        thr[i] = m - __builtin_fmaf(sar, 0x1.8p-17f, 4.0e-5f);
    }

    // ---- sweep 2: bit-identical recompute, branch-free mask accumulate ----
    u32 cm[8];
#pragma unroll
    for (int i = 0; i < 8; ++i) cm[i] = 0u;
#pragma unroll 2
    for (int k = 0; k < 18; ++k) {
        const int nt = 2 * k + hh;
        S2BODY(s_b + nt * 512 + lane * 8, k);
    }
#pragma unroll 2
    for (int k = 18; k < 32; ++k) {
        const int nt = 2 * k + hh;
        S2BODY(bfrag + (size_t)nt * 512 + lane * 8, k);
    }

    // ---- publish qualifiers to pair-shared lists (once, post-sweep) ----
    // cc = nt*16 + col16 = (k<<5) + (hh<<4) + col16
#pragma unroll
    for (int i = 0; i < 8; ++i) {
        u32 m = cm[i];
        if (m) {
            const int rloc = ((i >> 2) << 4) + quad * 4 + (i & 3);
            const u32 base = (u32)(hh << 4) + (u32)col16;
            do {
                int k = __ffs(m) - 1; m &= m - 1;
                u32 slot = atomicAdd(&cnt[rloc], 1u);
                if (slot < MAXC)
                    cand[rloc * MAXC + slot] = (ushortT)(((u32)k << 5) + base);
            } while (m);
        }
    }

    __syncthreads();   // pair lists complete

    if (hh != 0) return;   // tails on one wave per pair

    // ---- tail A: overflowed rows (rare) -> wave-cooperative exact scan ----
    u64 ovf = __ballot((lane < 32) && (cnt[lane & 31] > MAXC));
    while (ovf) {
        const int r = (int)(__ffsll((unsigned long long)ovf) - 1);
        ovf &= ovf - 1;
        const float* fp = h + (row0 + r) * DIM;   // wave-uniform row
        float fu[DIM];
#pragma unroll
        for (int i = 0; i < DIM; i += 4) {
            float4 x = *(const float4*)(fp + i);
            fu[i] = x.x; fu[i + 1] = x.y; fu[i + 2] = x.z; fu[i + 3] = x.w;
        }
        const float f2 = norm2_np(fu);
        u64 bk = ~0ull;
        for (int c = lane; c < EMB_N; c += 64) {
            const float* ep = emb + (size_t)c * DIM;
            float a = 0.f;
#pragma unroll
            for (int k = 0; k < DIM; ++k) a = __builtin_fmaf(fu[k], ep[k], a);
            float dd = (f2 + e2[c]) - (2.0f * a);
            u64 key = ((u64)enc_f32(dd) << 32) | (u32)c;
            if (key < bk) bk = key;
        }
#pragma unroll
        for (int m = 1; m < 64; m <<= 1) {
            u64 o = shflx_u64(bk, m);
            if (o < bk) bk = o;
        }
        if (lane == 0) { cand[r * MAXC] = (ushortT)(bk & 1023u); cnt[r] = 1; }
    }

    // ---- tail B: owner lane per row -> recheck + epilogue ----
    if (lane < 32) {
        const int row = (int)row0 + lane;
        const u32 n = cnt[lane];
        const float* f = h + (size_t)row * DIM;
        float fr[DIM];
#pragma unroll
        for (int i = 0; i < DIM; i += 4) {
            float4 x = *(const float4*)(f + i);
            fr[i] = x.x; fr[i + 1] = x.y; fr[i + 2] = x.z; fr[i + 3] = x.w;
        }
        int bidx;
        if (n == 1) {
            bidx = (int)cand[lane * MAXC];       // sole certified qualifier
        } else {
            const float f2 = norm2_np(fr);
            u64 best = ~0ull;
            for (u32 j = 0; j < n; ++j) {
                const u32 c = (u32)cand[lane * MAXC + j];
                const float* ep = emb + (size_t)c * DIM;
                float a = 0.f;
#pragma unroll
                for (int k = 0; k < DIM; ++k) a = __builtin_fmaf(fr[k], ep[k], a);  // BLAS chain
                float dd = (f2 + e2[c]) - (2.0f * a);     // exact numpy formula
                u64 key = ((u64)enc_f32(dd) << 32) | c;
                if (key < best) best = key;
            }
            bidx = (int)(best & 0xFFFFFFFFu);
        }

        const float* qv = emb + (size_t)bidx * DIM;
        float ps = 0.f;
#pragma unroll
        for (int i = 0; i < DIM; i += 4) {
            float4 qx; qx.x = qv[i]; qx.y = qv[i+1]; qx.z = qv[i+2]; qx.w = qv[i+3];
            float dx = qx.x - fr[i], dy = qx.y - fr[i+1], dz = qx.z - fr[i+2], dw = qx.w - fr[i+3];
            ps += dx * dx; ps += dy * dy; ps += dz * dz; ps += dw * dw;
            float4 o;
            o.x = fr[i]     + (qx.x - fr[i]);
            o.y = fr[i + 1] + (qx.y - fr[i + 1]);
            o.z = fr[i + 2] + (qx.z - fr[i + 2]);
            o.w = fr[i + 3] + (qx.w - fr[i + 3]);
            *(float4*)(out_q + (size_t)row * DIM + i) = o;
        }
        float m = ps * (1.0f / DIM);
        out_idx[row]  = (float)bidx;
        out_loss[row] = m * 0.1f + m * 0.1f;
    }
}

// ---------- fallback (R3-style) if workspace too small ----------
__global__ void e2_kernel(const float* __restrict__ emb, float* __restrict__ e2) {
#pragma clang fp contract(off)
    int c = blockIdx.x * blockDim.x + threadIdx.x;
    if (c >= EMB_N) return;
    const float* e = emb + (size_t)c * DIM;
    float tmp[DIM];
#pragma unroll
    for (int i = 0; i < DIM; ++i) tmp[i] = e[i];
    e2[c] = norm2_np(tmp);
}

__global__ __launch_bounds__(256) void vq_kernel(
    const float* __restrict__ h, const float* __restrict__ emb,
    const float* __restrict__ e2, float* __restrict__ out_q,
    float* __restrict__ out_idx, float* __restrict__ out_loss)
{
#pragma clang fp contract(off)
    const int v = blockIdx.x * blockDim.x + threadIdx.x;
    const float* f = h + (size_t)v * DIM;
    float fr[DIM];
#pragma unroll
    for (int i = 0; i < DIM; i += 4) {
        float4 x = *(const float4*)(f + i);
        fr[i] = x.x; fr[i + 1] = x.y; fr[i + 2] = x.z; fr[i + 3] = x.w;
    }
    const float f2 = norm2_np(fr);
    float best = 3.4e38f; int bidx = 0;
#pragma unroll 1
    for (int c = 0; c < EMB_N; ++c) {
        const float* e = emb + (size_t)c * DIM;
        float a0 = 0.f;
#pragma unroll
        for (int k = 0; k < DIM; ++k) a0 = __builtin_fmaf(fr[k], e[k], a0);
        float d0 = (f2 + e2[c]) - (2.0f * a0);
        if (d0 < best) { best = d0; bidx = c; }
    }
    const float* q = emb + (size_t)bidx * DIM;
    float ps = 0.f;
#pragma unroll
    for (int i = 0; i < DIM; i += 4) {
        float4 qx; qx.x = q[i]; qx.y = q[i+1]; qx.z = q[i+2]; qx.w = q[i+3];
        float dx = qx.x - fr[i], dy = qx.y - fr[i+1], dz = qx.z - fr[i+2], dw = qx.w - fr[i+3];
        ps += dx * dx; ps += dy * dy; ps += dz * dz; ps += dw * dw;
        float4 o;
        o.x = fr[i] + (qx.x - fr[i]); o.y = fr[i+1] + (qx.y - fr[i+1]);
        o.z = fr[i+2] + (qx.z - fr[i+2]); o.w = fr[i+3] + (qx.w - fr[i+3]);
        *(float4*)(out_q + (size_t)v * DIM + i) = o;
    }
    float m = ps * (1.0f / DIM);
    out_idx[v]  = (float)bidx;
    out_loss[v] = m * 0.1f + m * 0.1f;
}

extern "C" void kernel_launch(void* const* d_in, const int* in_sizes, int n_in,
                              void* d_out, int out_size, void* d_ws, size_t ws_size,
                              hipStream_t stream) {
    const float* h   = (const float*)d_in[0];
    const float* emb = (const float*)d_in[1];
    float* out = (float*)d_out;
    float* out_q    = out;                               // 4194304
    float* out_idx  = out + (size_t)NVEC * DIM;          // 131072
    float* out_loss = out + (size_t)NVEC * DIM + NVEC;   // 131072

    // ws layout: e2 4KB | bfrag 64KB
    float*   e2    = (float*)d_ws;
    ushortT* bfrag = (ushortT*)((char*)d_ws + 4096);
    const size_t need = 4096 + (size_t)EMB_N * DIM * sizeof(ushortT);

    if (ws_size >= need) {
        prep_kernel<<<16, 256, 0, stream>>>(emb, e2, bfrag);
        vq_scan<<<1024, 512, 0, stream>>>(h, emb, e2, bfrag,
                                          out_q, out_idx, out_loss);
    } else {
        e2_kernel<<<EMB_N / 256, 256, 0, stream>>>(emb, e2);
        vq_kernel<<<NVEC / 256, 256, 0, stream>>>(h, emb, e2, out_q, out_idx, out_loss);
    }
}